// Round 18
// baseline (86.159 us; speedup 1.0000x reference)
//
#include <hip/hip_runtime.h>
#include <math.h>

#define NUM_FREQS   64
#define NUM_BINS    128
#define NUM_QUERIES 32768
#define HEAD_DIM    128
#define EPS         1e-8f
#define NQB         16   // queries per block (4 waves x 4 j each)

// fast sqrt: bithack rsqrt guess + 1 Newton step (7 full-rate VALU ops = 14 cy
// vs v_sqrt_f32's ~16 cy). Rel err <= ~5e-4; validated on this data in R10.
__device__ __forceinline__ float fast_sqrt(float s) {
    float r0 = __int_as_float(0x5f375a86 - (__float_as_int(s) >> 1));
    float w  = fmaf(s * -0.5f * r0, r0, 1.5f);   // 1.5 - 0.5 s r0^2
    return s * (r0 * w);                          // s * rsqrt(s)
}

// ---------------------------------------------------------------------------
// Prep (probe only): probeA[f*128+b] = { -2Pr, -2Pi, Pr^2+Pi^2, -softplus }
//                    probeM[f*128+b] = mw
// ---------------------------------------------------------------------------
__global__ void prep_probe(const float* __restrict__ rp,
                           const float* __restrict__ wraw,
                           const float* __restrict__ mw,
                           float4* __restrict__ probeA,
                           float*  __restrict__ probeM) {
    int idx = blockIdx.x * 256 + threadIdx.x;    // idx = f*128 + b
    if (idx >= NUM_FREQS * NUM_BINS) return;
    int f = idx >> 7;
    int b = idx & 127;
    float pr = rp[b * HEAD_DIM + f];
    float pi = rp[b * HEAD_DIM + NUM_FREQS + f];
    float w  = wraw[b * NUM_FREQS + f];
    float sp = fmaxf(w, 0.0f) + log1pf(expf(-fabsf(w)));   // stable softplus
    probeA[idx] = make_float4(-2.0f * pr, -2.0f * pi,
                              fmaf(pr, pr, pi * pi), -sp);
    probeM[idx] = mw[b * NUM_FREQS + f];
}

// ---------------------------------------------------------------------------
// Main: block = 256 threads (4 waves); block owns 16 queries; wave w owns
// j in [4w, 4w+4); lane covers bins (lane, lane+64) -> 8 outputs per lane.
// In-block q-prep with XOR-SWIZZLED sri layout: physical 16B-unit
//   pu = u ^ ((row>>2)&7), u = j>>1.
// Scatter key (row>>2)&7 == c&7 varies over 8 values across lanes -> 4-way
// conflict (was 32-way at linear layout); main-loop reads are wave-uniform
// broadcasts at the swizzled address (conflict-free, float4-aligned).
// Main loop: expanded distance + NR fast_sqrt, depth-1 shadow pipeline on
// both pipes with sched_barrier(0) between issue and compute phases.
// ---------------------------------------------------------------------------
__global__ __launch_bounds__(256, 4) void main_kernel(
        const float4* __restrict__ probeA,
        const float*  __restrict__ probeM,
        const float*  __restrict__ Q,
        const float*  __restrict__ bias,
        float*        __restrict__ out) {
    __shared__ float2 sri[NUM_FREQS + 1][NQB];   // 8.1 KB, swizzled, +1 guard
    __shared__ float  sqm[NUM_FREQS + 1][NQB];   // 4.1 KB, linear,  +1 guard

    const int tid   = threadIdx.x;
    const int qbase = blockIdx.x * NQB;
    float2* sriF = &sri[0][0];

    // ---- in-block q-prep (swizzled scatter) ----
    // 16 rows x 32 float4-chunks; thread t holds chunk c = t&31 of rows
    // r1 = t>>5 (0..7) and r2 = r1+8; dims d = 4c..4c+3.
    {
        const float4* Qb = reinterpret_cast<const float4*>(Q + (size_t)qbase * HEAD_DIM);
        float4 v1 = Qb[tid];
        float4 v2 = Qb[tid + 256];
        const int c  = tid & 31;
        const int r1 = tid >> 5;
        const int r2 = r1 + 8;

        float s1 = fmaf(v1.x, v1.x, fmaf(v1.y, v1.y, fmaf(v1.z, v1.z, v1.w * v1.w)));
        float s2 = fmaf(v2.x, v2.x, fmaf(v2.y, v2.y, fmaf(v2.z, v2.z, v2.w * v2.w)));
        #pragma unroll
        for (int off = 1; off < 32; off <<= 1) {   // reduce within 32-lane group
            s1 += __shfl_xor(s1, off);
            s2 += __shfl_xor(s2, off);
        }
        float inv1 = 1.0f / (__builtin_amdgcn_sqrtf(s1) + EPS);
        float inv2 = 1.0f / (__builtin_amdgcn_sqrtf(s2) + EPS);

        // physical float2 index within a row, for columns r1 / r2:
        // pu(r) = ((r>>1) ^ (c&7))*2 + (r&1)   [key (row>>2)&7 == c&7]
        const int pu1 = (((r1 >> 1) ^ (c & 7)) << 1) | (r1 & 1);
        const int pu2 = (((r2 >> 1) ^ (c & 7)) << 1) | (r2 & 1);

        const float a1[4] = { v1.x, v1.y, v1.z, v1.w };
        const float a2[4] = { v2.x, v2.y, v2.z, v2.w };
        if (c < 16) {                          // real parts: rows d = 4c+k
            #pragma unroll
            for (int k = 0; k < 4; k++) {
                int row = 4 * c + k;
                sriF[row * NQB + pu1].x = a1[k] * inv1;
                sriF[row * NQB + pu2].x = a2[k] * inv2;
            }
        } else {                               // imag parts: rows 4(c-16)+k
            #pragma unroll
            for (int k = 0; k < 4; k++) {
                int row = 4 * (c - 16) + k;
                sriF[row * NQB + pu1].y = a1[k] * inv1;
                sriF[row * NQB + pu2].y = a2[k] * inv2;
            }
        }
    }
    __syncthreads();
    // qm plane from sri (swizzled reads, linear writes): 4 entries/thread.
    #pragma unroll
    for (int i = 0; i < 4; i++) {
        int e = i * 256 + tid;
        int f = e >> 4, j = e & 15;
        int pu = (((j >> 1) ^ ((f >> 2) & 7)) << 1) | (j & 1);
        float2 ri = sriF[f * NQB + pu];
        sqm[f][j] = __builtin_amdgcn_sqrtf(fmaf(ri.x, ri.x, fmaf(ri.y, ri.y, EPS)));
    }
    __syncthreads();

    const int lane = tid & 63;
    const int wave = tid >> 6;
    const int jb   = wave * 4;               // this wave's j-chunk base
    const int u0   = jb >> 1;                // logical 16B-unit of r01

    // swizzled float4 fetch of logical units (u0, u0+1) at row ff
#define SRI4(ff, uu) (*reinterpret_cast<const float4*>( \
        sriF + (ff) * NQB + ((((uu) ^ (((ff) >> 2) & 7))) << 1)))

    float b0 = bias[lane];
    float b1 = bias[64 + lane];

    float acc0[4], acc1[4];
    #pragma unroll
    for (int p = 0; p < 4; p++) { acc0[p] = 0.0f; acc1[p] = 0.0f; }

    const float4* pA = probeA + lane;        // advances by 128 per f
    const float*  pM = probeM + lane;

    // Prologue: f = 0 into the live registers (both pipes).
    float4 P0  = pA[0];
    float4 P1  = pA[64];
    float  w0  = pM[0];
    float  w1  = pM[64];
    float4 r01 = SRI4(0, u0);
    float4 r23 = SRI4(0, u0 + 1);
    float4 qm4 = *reinterpret_cast<const float4*>(&sqm[0][jb]);

    #pragma unroll 4
    for (int f = 0; f < NUM_FREQS; f++) {
        // ---- issue phase: LDS + VMEM for f+1 into shadow registers ----
        float4 r01n = SRI4(f + 1, u0);
        float4 r23n = SRI4(f + 1, u0 + 1);
        float4 qm4n = *reinterpret_cast<const float4*>(&sqm[f + 1][jb]);
        pA += NUM_BINS; pM += NUM_BINS;
        float4 P0n = pA[0];                  // f=63: lands in probeM/margin, unused
        float4 P1n = pA[64];
        float  w0n = pM[0];
        float  w1n = pM[64];
        __builtin_amdgcn_sched_barrier(0);   // keep issue phase above compute

        // ---- compute phase (uses current registers) ----
        const float qrv[4] = { r01.x, r01.z, r23.x, r23.z };
        const float qiv[4] = { r01.y, r01.w, r23.y, r23.w };
        const float qmv[4] = { qm4.x, qm4.y, qm4.z, qm4.w };

        #pragma unroll
        for (int p = 0; p < 4; p++) {
            float qr = qrv[p], qi = qiv[p], qm = qmv[p];
            {   // bin = lane
                float a = fmaf(qm, qm, P0.z);
                a = fmaf(P0.x, qr, a);
                a = fmaf(P0.y, qi, a);
                float d = fast_sqrt(a);
                acc0[p] = fmaf(d, P0.w, fmaf(qm, w0, acc0[p]));
            }
            {   // bin = lane + 64
                float a = fmaf(qm, qm, P1.z);
                a = fmaf(P1.x, qr, a);
                a = fmaf(P1.y, qi, a);
                float d = fast_sqrt(a);
                acc1[p] = fmaf(d, P1.w, fmaf(qm, w1, acc1[p]));
            }
        }

        // ---- rotate shadows -> live ----
        r01 = r01n; r23 = r23n; qm4 = qm4n;
        P0 = P0n; P1 = P1n; w0 = w0n; w1 = w1n;
    }
#undef SRI4

    #pragma unroll
    for (int p = 0; p < 4; p++) {
        size_t row = (size_t)(qbase + jb + p) * NUM_BINS;
        out[row + lane]      = acc0[p] + b0;     // coalesced
        out[row + 64 + lane] = acc1[p] + b1;     // coalesced
    }
}

// ---------------------------------------------------------------------------
// Fallback (only if ws_size is too small): fully self-contained, slower.
// ---------------------------------------------------------------------------
__global__ void fallback_kernel(const float* __restrict__ Q,
                                const float* __restrict__ rp,
                                const float* __restrict__ wraw,
                                const float* __restrict__ mw,
                                const float* __restrict__ bias,
                                float* __restrict__ out) {
    __shared__ float qn[HEAD_DIM];
    __shared__ float qmag[NUM_FREQS];
    __shared__ float red[NUM_BINS];
    const int t = threadIdx.x;
    const int q = blockIdx.x;

    float v = Q[(size_t)q * HEAD_DIM + t];
    red[t] = v * v;
    __syncthreads();
    for (int s = 64; s > 0; s >>= 1) {
        if (t < s) red[t] += red[t + s];
        __syncthreads();
    }
    float inv = 1.0f / (__builtin_amdgcn_sqrtf(red[0]) + EPS);
    qn[t] = v * inv;
    __syncthreads();
    if (t < NUM_FREQS) {
        float a = qn[t], c = qn[t + NUM_FREQS];
        qmag[t] = __builtin_amdgcn_sqrtf(fmaf(a, a, fmaf(c, c, EPS)));
    }
    __syncthreads();

    const int b = t;
    float acc = 0.0f;
    for (int f = 0; f < NUM_FREQS; f++) {
        float pr = rp[(size_t)b * HEAD_DIM + f];
        float pi = rp[(size_t)b * HEAD_DIM + NUM_FREQS + f];
        float w  = wraw[(size_t)b * NUM_FREQS + f];
        float ew = -(fmaxf(w, 0.0f) + log1pf(expf(-fabsf(w))));
        float er = pr - qn[f];
        float ei = pi - qn[f + NUM_FREQS];
        float d  = __builtin_amdgcn_sqrtf(fmaf(er, er, fmaf(ei, ei, EPS)));
        acc = fmaf(d, ew, fmaf(qmag[f], mw[(size_t)b * NUM_FREQS + f], acc));
    }
    out[(size_t)q * NUM_BINS + b] = acc + bias[b];
}

// ---------------------------------------------------------------------------
extern "C" void kernel_launch(void* const* d_in, const int* in_sizes, int n_in,
                              void* d_out, int out_size, void* d_ws, size_t ws_size,
                              hipStream_t stream) {
    const float* Q    = (const float*)d_in[0];
    const float* rp   = (const float*)d_in[1];
    const float* wraw = (const float*)d_in[2];
    const float* mw   = (const float*)d_in[3];
    const float* bias = (const float*)d_in[4];
    float* out = (float*)d_out;

    const size_t pABytes = (size_t)NUM_FREQS * NUM_BINS * sizeof(float4);  // 128 KiB
    const size_t pMBytes = (size_t)NUM_FREQS * NUM_BINS * sizeof(float);   //  32 KiB
    const size_t need    = pABytes + pMBytes + 8192;   // + margin for f=63 prefetch

    if (ws_size >= need) {
        float4* probeA = (float4*)d_ws;
        float*  probeM = (float*)((char*)d_ws + pABytes);

        hipLaunchKernelGGL(prep_probe, dim3(32), dim3(256), 0, stream,
                           rp, wraw, mw, probeA, probeM);
        hipLaunchKernelGGL(main_kernel, dim3(NUM_QUERIES / NQB), dim3(256), 0,
                           stream, probeA, probeM, Q, bias, out);
    } else {
        hipLaunchKernelGGL(fallback_kernel, dim3(NUM_QUERIES), dim3(NUM_BINS), 0,
                           stream, Q, rp, wraw, mw, bias, out);
    }
}

// Round 19
// 65.388 us; speedup vs baseline: 1.3177x; 1.3177x over previous
//
#include <hip/hip_runtime.h>
#include <math.h>

#define NUM_FREQS   64
#define NUM_BINS    128
#define NUM_QUERIES 32768
#define HEAD_DIM    128
#define EPS         1e-8f
#define NQB         16   // queries per block (4 waves x 4 j each)
#define SRP         (NQB + 1)   // padded sri row stride (17 float2) -> scatter 4-way

// ---------------------------------------------------------------------------
// Prep (probe only): probeA[f*128+b] = { -2Pr, -2Pi, Pr^2+Pi^2, -softplus }
//                    probeM[f*128+b] = mw
// ---------------------------------------------------------------------------
__global__ void prep_probe(const float* __restrict__ rp,
                           const float* __restrict__ wraw,
                           const float* __restrict__ mw,
                           float4* __restrict__ probeA,
                           float*  __restrict__ probeM) {
    int idx = blockIdx.x * 256 + threadIdx.x;    // idx = f*128 + b
    if (idx >= NUM_FREQS * NUM_BINS) return;
    int f = idx >> 7;
    int b = idx & 127;
    float pr = rp[b * HEAD_DIM + f];
    float pi = rp[b * HEAD_DIM + NUM_FREQS + f];
    float w  = wraw[b * NUM_FREQS + f];
    float sp = fmaxf(w, 0.0f) + log1pf(expf(-fabsf(w)));   // stable softplus
    probeA[idx] = make_float4(-2.0f * pr, -2.0f * pi,
                              fmaf(pr, pr, pi * pi), -sp);
    probeM[idx] = mw[b * NUM_FREQS + f];
}

// ---------------------------------------------------------------------------
// Main: block = 256 threads (4 waves); block owns 16 queries; wave w owns
// j in [4w, 4w+4); lane covers bins (lane, lane+64) -> 8 outputs per lane.
// In-block q-prep: coalesced Q read, 32-lane shfl_xor row-norm, scatter into
// PADDED sri (row stride 17 float2): scatter bank = (8c+34k+2r) mod 32 ->
// 4-way conflict (was 32-way), zero extra VALU in the main loop.
// Main loop: expanded distance s = C'' + qm^2 - 2Pr*qr - 2Pi*qi, v_sqrt_f32,
// depth-1 shadow pipeline on both pipes, sched_barrier(0) per iteration.
// q-reads are 8B-aligned float2 broadcasts (ds_read2_b64-pairable, uniform).
// ---------------------------------------------------------------------------
__global__ __launch_bounds__(256, 4) void main_kernel(
        const float4* __restrict__ probeA,
        const float*  __restrict__ probeM,
        const float*  __restrict__ Q,
        const float*  __restrict__ bias,
        float*        __restrict__ out) {
    __shared__ float2 sri[NUM_FREQS + 1][SRP];   // 8.8 KB, padded, +1 guard row
    __shared__ float  sqm[NUM_FREQS + 1][NQB];   // 4.1 KB, linear, +1 guard row

    const int tid   = threadIdx.x;
    const int qbase = blockIdx.x * NQB;

    // ---- in-block q-prep ----
    // 16 rows x 32 float4-chunks; thread t holds chunk c = t&31 of rows
    // r1 = t>>5 (0..7) and r2 = r1+8; dims d = 4c..4c+3.
    {
        const float4* Qb = reinterpret_cast<const float4*>(Q + (size_t)qbase * HEAD_DIM);
        float4 v1 = Qb[tid];
        float4 v2 = Qb[tid + 256];
        const int c  = tid & 31;
        const int r1 = tid >> 5;
        const int r2 = r1 + 8;

        float s1 = fmaf(v1.x, v1.x, fmaf(v1.y, v1.y, fmaf(v1.z, v1.z, v1.w * v1.w)));
        float s2 = fmaf(v2.x, v2.x, fmaf(v2.y, v2.y, fmaf(v2.z, v2.z, v2.w * v2.w)));
        #pragma unroll
        for (int off = 1; off < 32; off <<= 1) {   // reduce within 32-lane group
            s1 += __shfl_xor(s1, off);
            s2 += __shfl_xor(s2, off);
        }
        float inv1 = 1.0f / (__builtin_amdgcn_sqrtf(s1) + EPS);
        float inv2 = 1.0f / (__builtin_amdgcn_sqrtf(s2) + EPS);

        const float a1[4] = { v1.x, v1.y, v1.z, v1.w };
        const float a2[4] = { v2.x, v2.y, v2.z, v2.w };
        if (c < 16) {                          // real parts: rows d = 4c+k
            #pragma unroll
            for (int k = 0; k < 4; k++) {
                int row = 4 * c + k;
                sri[row][r1].x = a1[k] * inv1;
                sri[row][r2].x = a2[k] * inv2;
            }
        } else {                               // imag parts: rows 4(c-16)+k
            #pragma unroll
            for (int k = 0; k < 4; k++) {
                int row = 4 * (c - 16) + k;
                sri[row][r1].y = a1[k] * inv1;
                sri[row][r2].y = a2[k] * inv2;
            }
        }
    }
    __syncthreads();
    // qm plane from sri: 4 entries/thread (2-way banked reads, linear writes).
    #pragma unroll
    for (int i = 0; i < 4; i++) {
        int e = i * 256 + tid;
        int f = e >> 4, j = e & 15;
        float2 ri = sri[f][j];
        sqm[f][j] = __builtin_amdgcn_sqrtf(fmaf(ri.x, ri.x, fmaf(ri.y, ri.y, EPS)));
    }
    __syncthreads();

    const int lane = tid & 63;
    const int wave = tid >> 6;
    const int jb   = wave * 4;               // this wave's j-chunk base

    float b0 = bias[lane];
    float b1 = bias[64 + lane];

    float acc0[4], acc1[4];
    #pragma unroll
    for (int p = 0; p < 4; p++) { acc0[p] = 0.0f; acc1[p] = 0.0f; }

    const float4* pA = probeA + lane;        // advances by 128 per f
    const float*  pM = probeM + lane;

    // Prologue: f = 0 into the live registers (both pipes).
    float4 P0  = pA[0];
    float4 P1  = pA[64];
    float  w0  = pM[0];
    float  w1  = pM[64];
    float2 q0  = sri[0][jb];
    float2 q1  = sri[0][jb + 1];
    float2 q2  = sri[0][jb + 2];
    float2 q3  = sri[0][jb + 3];
    float4 qm4 = *reinterpret_cast<const float4*>(&sqm[0][jb]);

    #pragma unroll 4
    for (int f = 0; f < NUM_FREQS; f++) {
        // ---- issue phase: LDS + VMEM for f+1 into shadow registers ----
        float2 q0n = sri[f + 1][jb];
        float2 q1n = sri[f + 1][jb + 1];
        float2 q2n = sri[f + 1][jb + 2];
        float2 q3n = sri[f + 1][jb + 3];
        float4 qm4n = *reinterpret_cast<const float4*>(&sqm[f + 1][jb]);
        pA += NUM_BINS; pM += NUM_BINS;
        float4 P0n = pA[0];                  // f=63: lands in probeM/margin, unused
        float4 P1n = pA[64];
        float  w0n = pM[0];
        float  w1n = pM[64];
        __builtin_amdgcn_sched_barrier(0);   // keep issue phase above compute

        // ---- compute phase (uses current registers) ----
        const float qrv[4] = { q0.x, q1.x, q2.x, q3.x };
        const float qiv[4] = { q0.y, q1.y, q2.y, q3.y };
        const float qmv[4] = { qm4.x, qm4.y, qm4.z, qm4.w };

        #pragma unroll
        for (int p = 0; p < 4; p++) {
            float qr = qrv[p], qi = qiv[p], qm = qmv[p];
            {   // bin = lane
                float a = fmaf(qm, qm, P0.z);
                a = fmaf(P0.x, qr, a);
                a = fmaf(P0.y, qi, a);
                float d = __builtin_amdgcn_sqrtf(a);
                acc0[p] = fmaf(d, P0.w, fmaf(qm, w0, acc0[p]));
            }
            {   // bin = lane + 64
                float a = fmaf(qm, qm, P1.z);
                a = fmaf(P1.x, qr, a);
                a = fmaf(P1.y, qi, a);
                float d = __builtin_amdgcn_sqrtf(a);
                acc1[p] = fmaf(d, P1.w, fmaf(qm, w1, acc1[p]));
            }
        }

        // ---- rotate shadows -> live ----
        q0 = q0n; q1 = q1n; q2 = q2n; q3 = q3n; qm4 = qm4n;
        P0 = P0n; P1 = P1n; w0 = w0n; w1 = w1n;
    }

    #pragma unroll
    for (int p = 0; p < 4; p++) {
        size_t row = (size_t)(qbase + jb + p) * NUM_BINS;
        out[row + lane]      = acc0[p] + b0;     // coalesced
        out[row + 64 + lane] = acc1[p] + b1;     // coalesced
    }
}

// ---------------------------------------------------------------------------
// Fallback (only if ws_size is too small): fully self-contained, slower.
// ---------------------------------------------------------------------------
__global__ void fallback_kernel(const float* __restrict__ Q,
                                const float* __restrict__ rp,
                                const float* __restrict__ wraw,
                                const float* __restrict__ mw,
                                const float* __restrict__ bias,
                                float* __restrict__ out) {
    __shared__ float qn[HEAD_DIM];
    __shared__ float qmag[NUM_FREQS];
    __shared__ float red[NUM_BINS];
    const int t = threadIdx.x;
    const int q = blockIdx.x;

    float v = Q[(size_t)q * HEAD_DIM + t];
    red[t] = v * v;
    __syncthreads();
    for (int s = 64; s > 0; s >>= 1) {
        if (t < s) red[t] += red[t + s];
        __syncthreads();
    }
    float inv = 1.0f / (__builtin_amdgcn_sqrtf(red[0]) + EPS);
    qn[t] = v * inv;
    __syncthreads();
    if (t < NUM_FREQS) {
        float a = qn[t], c = qn[t + NUM_FREQS];
        qmag[t] = __builtin_amdgcn_sqrtf(fmaf(a, a, fmaf(c, c, EPS)));
    }
    __syncthreads();

    const int b = t;
    float acc = 0.0f;
    for (int f = 0; f < NUM_FREQS; f++) {
        float pr = rp[(size_t)b * HEAD_DIM + f];
        float pi = rp[(size_t)b * HEAD_DIM + NUM_FREQS + f];
        float w  = wraw[(size_t)b * NUM_FREQS + f];
        float ew = -(fmaxf(w, 0.0f) + log1pf(expf(-fabsf(w))));
        float er = pr - qn[f];
        float ei = pi - qn[f + NUM_FREQS];
        float d  = __builtin_amdgcn_sqrtf(fmaf(er, er, fmaf(ei, ei, EPS)));
        acc = fmaf(d, ew, fmaf(qmag[f], mw[(size_t)b * NUM_FREQS + f], acc));
    }
    out[(size_t)q * NUM_BINS + b] = acc + bias[b];
}

// ---------------------------------------------------------------------------
extern "C" void kernel_launch(void* const* d_in, const int* in_sizes, int n_in,
                              void* d_out, int out_size, void* d_ws, size_t ws_size,
                              hipStream_t stream) {
    const float* Q    = (const float*)d_in[0];
    const float* rp   = (const float*)d_in[1];
    const float* wraw = (const float*)d_in[2];
    const float* mw   = (const float*)d_in[3];
    const float* bias = (const float*)d_in[4];
    float* out = (float*)d_out;

    const size_t pABytes = (size_t)NUM_FREQS * NUM_BINS * sizeof(float4);  // 128 KiB
    const size_t pMBytes = (size_t)NUM_FREQS * NUM_BINS * sizeof(float);   //  32 KiB
    const size_t need    = pABytes + pMBytes + 8192;   // + margin for f=63 prefetch

    if (ws_size >= need) {
        float4* probeA = (float4*)d_ws;
        float*  probeM = (float*)((char*)d_ws + pABytes);

        hipLaunchKernelGGL(prep_probe, dim3(32), dim3(256), 0, stream,
                           rp, wraw, mw, probeA, probeM);
        hipLaunchKernelGGL(main_kernel, dim3(NUM_QUERIES / NQB), dim3(256), 0,
                           stream, probeA, probeM, Q, bias, out);
    } else {
        hipLaunchKernelGGL(fallback_kernel, dim3(NUM_QUERIES), dim3(NUM_BINS), 0,
                           stream, Q, rp, wraw, mw, bias, out);
    }
}

// Round 20
// 64.180 us; speedup vs baseline: 1.3425x; 1.0188x over previous
//
#include <hip/hip_runtime.h>
#include <math.h>

#define NUM_FREQS   64
#define NUM_BINS    128
#define NUM_QUERIES 32768
#define HEAD_DIM    128
#define EPS         1e-8f
#define NQB         16   // queries per block (4 waves x 4 j each)
#define SRP         (NQB + 1)   // padded sri row stride (17 float2) -> scatter 4-way

// ---------------------------------------------------------------------------
// Prep (probe only): probeA[f*128+b] = { -2Pr, -2Pi, Pr^2+Pi^2, -softplus }
//                    probeM[f*128+b] = mw
// ---------------------------------------------------------------------------
__global__ void prep_probe(const float* __restrict__ rp,
                           const float* __restrict__ wraw,
                           const float* __restrict__ mw,
                           float4* __restrict__ probeA,
                           float*  __restrict__ probeM) {
    int idx = blockIdx.x * 256 + threadIdx.x;    // idx = f*128 + b
    if (idx >= NUM_FREQS * NUM_BINS) return;
    int f = idx >> 7;
    int b = idx & 127;
    float pr = rp[b * HEAD_DIM + f];
    float pi = rp[b * HEAD_DIM + NUM_FREQS + f];
    float w  = wraw[b * NUM_FREQS + f];
    float sp = fmaxf(w, 0.0f) + log1pf(expf(-fabsf(w)));   // stable softplus
    probeA[idx] = make_float4(-2.0f * pr, -2.0f * pi,
                              fmaf(pr, pr, pi * pi), -sp);
    probeM[idx] = mw[b * NUM_FREQS + f];
}

// ---------------------------------------------------------------------------
// Main: block = 256 threads (4 waves); block owns 16 queries; wave w owns
// j in [4w, 4w+4); lane covers bins (lane, lane+64) -> 8 outputs per lane.
// In-block q-prep (padded sri, 4-way scatter). Main loop: expanded distance
// s = C'' + qm^2 - 2Pr*qr - 2Pi*qi, v_sqrt_f32.
// HAND MODULO-2 SCHEDULE: two statically-named register sets A/B ping-pong —
// issue B(f+1); SB; compute A(f); issue A(f+2); SB; compute B(f+1).
// No shadow->live rotation movs (R19 paid ~13 movs/f across the barrier).
// ---------------------------------------------------------------------------
__global__ __launch_bounds__(256, 4) void main_kernel(
        const float4* __restrict__ probeA,
        const float*  __restrict__ probeM,
        const float*  __restrict__ Q,
        const float*  __restrict__ bias,
        float*        __restrict__ out) {
    __shared__ float2 sri[NUM_FREQS + 1][SRP];   // padded, +1 guard row
    __shared__ float  sqm[NUM_FREQS + 1][NQB];   // linear, +1 guard row

    const int tid   = threadIdx.x;
    const int qbase = blockIdx.x * NQB;

    // ---- in-block q-prep ----
    {
        const float4* Qb = reinterpret_cast<const float4*>(Q + (size_t)qbase * HEAD_DIM);
        float4 v1 = Qb[tid];
        float4 v2 = Qb[tid + 256];
        const int c  = tid & 31;
        const int r1 = tid >> 5;
        const int r2 = r1 + 8;

        float s1 = fmaf(v1.x, v1.x, fmaf(v1.y, v1.y, fmaf(v1.z, v1.z, v1.w * v1.w)));
        float s2 = fmaf(v2.x, v2.x, fmaf(v2.y, v2.y, fmaf(v2.z, v2.z, v2.w * v2.w)));
        #pragma unroll
        for (int off = 1; off < 32; off <<= 1) {   // reduce within 32-lane group
            s1 += __shfl_xor(s1, off);
            s2 += __shfl_xor(s2, off);
        }
        float inv1 = 1.0f / (__builtin_amdgcn_sqrtf(s1) + EPS);
        float inv2 = 1.0f / (__builtin_amdgcn_sqrtf(s2) + EPS);

        const float a1[4] = { v1.x, v1.y, v1.z, v1.w };
        const float a2[4] = { v2.x, v2.y, v2.z, v2.w };
        if (c < 16) {                          // real parts: rows d = 4c+k
            #pragma unroll
            for (int k = 0; k < 4; k++) {
                int row = 4 * c + k;
                sri[row][r1].x = a1[k] * inv1;
                sri[row][r2].x = a2[k] * inv2;
            }
        } else {                               // imag parts: rows 4(c-16)+k
            #pragma unroll
            for (int k = 0; k < 4; k++) {
                int row = 4 * (c - 16) + k;
                sri[row][r1].y = a1[k] * inv1;
                sri[row][r2].y = a2[k] * inv2;
            }
        }
    }
    __syncthreads();
    #pragma unroll
    for (int i = 0; i < 4; i++) {
        int e = i * 256 + tid;
        int f = e >> 4, j = e & 15;
        float2 ri = sri[f][j];
        sqm[f][j] = __builtin_amdgcn_sqrtf(fmaf(ri.x, ri.x, fmaf(ri.y, ri.y, EPS)));
    }
    __syncthreads();

    const int lane = tid & 63;
    const int wave = tid >> 6;
    const int jb   = wave * 4;               // this wave's j-chunk base

    float b0 = bias[lane];
    float b1 = bias[64 + lane];

    float acc0[4], acc1[4];
    #pragma unroll
    for (int p = 0; p < 4; p++) { acc0[p] = 0.0f; acc1[p] = 0.0f; }

    const float4* pA = probeA + lane;        // walks +128 float4 per f
    const float*  pM = probeM + lane;

// compute one f using a named register set (4 j x 2 bins)
#define CSTEP(P0_, P1_, w0_, w1_, qa_, qb_, qc_, qd_, qm_)                   \
    {                                                                        \
        const float qrv[4] = { qa_.x, qb_.x, qc_.x, qd_.x };                 \
        const float qiv[4] = { qa_.y, qb_.y, qc_.y, qd_.y };                 \
        const float qmv[4] = { qm_.x, qm_.y, qm_.z, qm_.w };                 \
        _Pragma("unroll")                                                    \
        for (int p = 0; p < 4; p++) {                                        \
            float qr = qrv[p], qi = qiv[p], qm = qmv[p];                     \
            float a0 = fmaf(qm, qm, P0_.z);                                  \
            a0 = fmaf(P0_.x, qr, a0);                                        \
            a0 = fmaf(P0_.y, qi, a0);                                        \
            float d0 = __builtin_amdgcn_sqrtf(a0);                           \
            acc0[p] = fmaf(d0, P0_.w, fmaf(qm, w0_, acc0[p]));               \
            float a1 = fmaf(qm, qm, P1_.z);                                  \
            a1 = fmaf(P1_.x, qr, a1);                                        \
            a1 = fmaf(P1_.y, qi, a1);                                        \
            float d1 = __builtin_amdgcn_sqrtf(a1);                           \
            acc1[p] = fmaf(d1, P1_.w, fmaf(qm, w1_, acc1[p]));               \
        }                                                                    \
    }

    // Prologue: set A <- f = 0.
    float4 A_P0 = pA[0], A_P1 = pA[64];
    float  A_w0 = pM[0], A_w1 = pM[64];
    float2 A_q0 = sri[0][jb],     A_q1 = sri[0][jb + 1];
    float2 A_q2 = sri[0][jb + 2], A_q3 = sri[0][jb + 3];
    float4 A_qm = *reinterpret_cast<const float4*>(&sqm[0][jb]);
    pA += NUM_BINS; pM += NUM_BINS;

    #pragma unroll 2
    for (int g = 0; g < NUM_FREQS / 2; ++g) {
        const int f1 = 2 * g + 1;
        // ---- issue set B <- f1 ----
        float4 B_P0 = pA[0], B_P1 = pA[64];
        float  B_w0 = pM[0], B_w1 = pM[64];
        float2 B_q0 = sri[f1][jb],     B_q1 = sri[f1][jb + 1];
        float2 B_q2 = sri[f1][jb + 2], B_q3 = sri[f1][jb + 3];
        float4 B_qm = *reinterpret_cast<const float4*>(&sqm[f1][jb]);
        pA += NUM_BINS; pM += NUM_BINS;
        __builtin_amdgcn_sched_barrier(0);
        // ---- compute A (f1-1) ----
        CSTEP(A_P0, A_P1, A_w0, A_w1, A_q0, A_q1, A_q2, A_q3, A_qm);

        // ---- issue set A <- f1+1 (g=31: row 64 = guard / probeM margin) ----
        A_P0 = pA[0]; A_P1 = pA[64];
        A_w0 = pM[0]; A_w1 = pM[64];
        A_q0 = sri[f1 + 1][jb];     A_q1 = sri[f1 + 1][jb + 1];
        A_q2 = sri[f1 + 1][jb + 2]; A_q3 = sri[f1 + 1][jb + 3];
        A_qm = *reinterpret_cast<const float4*>(&sqm[f1 + 1][jb]);
        pA += NUM_BINS; pM += NUM_BINS;
        __builtin_amdgcn_sched_barrier(0);
        // ---- compute B (f1) ----
        CSTEP(B_P0, B_P1, B_w0, B_w1, B_q0, B_q1, B_q2, B_q3, B_qm);
    }
#undef CSTEP

    #pragma unroll
    for (int p = 0; p < 4; p++) {
        size_t row = (size_t)(qbase + jb + p) * NUM_BINS;
        out[row + lane]      = acc0[p] + b0;     // coalesced
        out[row + 64 + lane] = acc1[p] + b1;     // coalesced
    }
}

// ---------------------------------------------------------------------------
// Fallback (only if ws_size is too small): fully self-contained, slower.
// ---------------------------------------------------------------------------
__global__ void fallback_kernel(const float* __restrict__ Q,
                                const float* __restrict__ rp,
                                const float* __restrict__ wraw,
                                const float* __restrict__ mw,
                                const float* __restrict__ bias,
                                float* __restrict__ out) {
    __shared__ float qn[HEAD_DIM];
    __shared__ float qmag[NUM_FREQS];
    __shared__ float red[NUM_BINS];
    const int t = threadIdx.x;
    const int q = blockIdx.x;

    float v = Q[(size_t)q * HEAD_DIM + t];
    red[t] = v * v;
    __syncthreads();
    for (int s = 64; s > 0; s >>= 1) {
        if (t < s) red[t] += red[t + s];
        __syncthreads();
    }
    float inv = 1.0f / (__builtin_amdgcn_sqrtf(red[0]) + EPS);
    qn[t] = v * inv;
    __syncthreads();
    if (t < NUM_FREQS) {
        float a = qn[t], c = qn[t + NUM_FREQS];
        qmag[t] = __builtin_amdgcn_sqrtf(fmaf(a, a, fmaf(c, c, EPS)));
    }
    __syncthreads();

    const int b = t;
    float acc = 0.0f;
    for (int f = 0; f < NUM_FREQS; f++) {
        float pr = rp[(size_t)b * HEAD_DIM + f];
        float pi = rp[(size_t)b * HEAD_DIM + NUM_FREQS + f];
        float w  = wraw[(size_t)b * NUM_FREQS + f];
        float ew = -(fmaxf(w, 0.0f) + log1pf(expf(-fabsf(w))));
        float er = pr - qn[f];
        float ei = pi - qn[f + NUM_FREQS];
        float d  = __builtin_amdgcn_sqrtf(fmaf(er, er, fmaf(ei, ei, EPS)));
        acc = fmaf(d, ew, fmaf(qmag[f], mw[(size_t)b * NUM_FREQS + f], acc));
    }
    out[(size_t)q * NUM_BINS + b] = acc + bias[b];
}

// ---------------------------------------------------------------------------
extern "C" void kernel_launch(void* const* d_in, const int* in_sizes, int n_in,
                              void* d_out, int out_size, void* d_ws, size_t ws_size,
                              hipStream_t stream) {
    const float* Q    = (const float*)d_in[0];
    const float* rp   = (const float*)d_in[1];
    const float* wraw = (const float*)d_in[2];
    const float* mw   = (const float*)d_in[3];
    const float* bias = (const float*)d_in[4];
    float* out = (float*)d_out;

    const size_t pABytes = (size_t)NUM_FREQS * NUM_BINS * sizeof(float4);  // 128 KiB
    const size_t pMBytes = (size_t)NUM_FREQS * NUM_BINS * sizeof(float);   //  32 KiB
    const size_t need    = pABytes + pMBytes + 8192;   // + margin for f=64 prefetch

    if (ws_size >= need) {
        float4* probeA = (float4*)d_ws;
        float*  probeM = (float*)((char*)d_ws + pABytes);

        hipLaunchKernelGGL(prep_probe, dim3(32), dim3(256), 0, stream,
                           rp, wraw, mw, probeA, probeM);
        hipLaunchKernelGGL(main_kernel, dim3(NUM_QUERIES / NQB), dim3(256), 0,
                           stream, probeA, probeM, Q, bias, out);
    } else {
        hipLaunchKernelGGL(fallback_kernel, dim3(NUM_QUERIES), dim3(NUM_BINS), 0,
                           stream, Q, rp, wraw, mw, bias, out);
    }
}